// Round 7
// baseline (194.079 us; speedup 1.0000x reference)
//
#include <hip/hip_runtime.h>
#include <hip/hip_bf16.h>

#define EDIM 128
#define MDIM 8
#define ADIM 64
#define NFR  50
#define NCOL (NFR * MDIM)   // 400
#define NSLICE 64           // contention slices for softmax denominator atomics

typedef __attribute__((ext_vector_type(8))) short short8;
typedef __attribute__((ext_vector_type(4))) float f32x4;
typedef __attribute__((ext_vector_type(4))) unsigned uint4v;

__device__ __forceinline__ float waveReduceSum(float v) {
    #pragma unroll
    for (int s = 32; s >= 1; s >>= 1) v += __shfl_xor(v, s, 64);
    return v;
}
// packed f32->bf16 (RNE): compiler emits v_cvt_pk_bf16_f32
__device__ __forceinline__ unsigned cvt2u(float lo, float hi) {
    union { __hip_bfloat162 h; unsigned u; } cv;
    cv.h = __float22bfloat162_rn(float2{lo, hi});
    return cv.u;
}
__device__ __forceinline__ short8 pack8(float4 a, float4 b) {
    union { uint4v u; short8 s; } cv;
    cv.u[0] = cvt2u(a.x, a.y);
    cv.u[1] = cvt2u(a.z, a.w);
    cv.u[2] = cvt2u(b.x, b.y);
    cv.u[3] = cvt2u(b.z, b.w);
    return cv.s;
}
__device__ __forceinline__ short f2bf(float x) {
    unsigned u = __float_as_uint(x);
    u += 0x7FFFu + ((u >> 16) & 1u);
    return (short)(u >> 16);
}
__device__ __forceinline__ float bf2f(short s) {
    return __uint_as_float(((unsigned)(unsigned short)s) << 16);
}
// Swizzled A-frag layout (k3 only). Block (Mt=r>>4, Kt=e>>5) of 512 shorts;
// within it slot = (q*16+(r&15)) ^ (q<<1), q=(e>>3)&3.
__device__ __forceinline__ int fragOff(int r, int e) {   // e multiple of 8
    int q = (e >> 3) & 3;
    int slot = (q * 16 + (r & 15)) ^ (q << 1);
    int block = ((r >> 4) << 2) | (e >> 5);
    return (block * 64 + slot) * 8;
}
__device__ __forceinline__ int slotR(int l) { return l ^ (((l >> 4) & 3) << 1); }

// k0: pre-pack WA (B-frags 4Nt x 4Kt) and Key (4Kt, N padded 8->16 with 0);
// also zero the softmax-denominator slices (harness poisons ws each iter).
__global__ __launch_bounds__(256)
void k0_prep(const float* __restrict__ WA, const float* __restrict__ Key,
             short* __restrict__ WAfrag, short* __restrict__ Keyfrag,
             float* __restrict__ Ssum)
{
    int t = blockIdx.x * 256 + threadIdx.x;
    for (int i = t; i < NSLICE * NCOL; i += 5 * 256) Ssum[i] = 0.f;
    if (t < 1024) {
        int lane = t & 63;
        int Kt = (t >> 6) & 3;
        int Nt = t >> 8;
        int n  = Nt * 16 + (lane & 15);
        int k0 = Kt * 32 + (lane >> 4) * 8;
        short8 v;
        #pragma unroll
        for (int j = 0; j < 8; ++j) v[j] = f2bf(WA[(size_t)(k0 + j) * ADIM + n]);
        *(short8*)(WAfrag + (size_t)t * 8) = v;
    } else if (t < 1280) {
        int i = t - 1024;
        int lane = i & 63;
        int Kt = i >> 6;
        int n  = lane & 15;
        int k0 = Kt * 32 + (lane >> 4) * 8;
        short8 v;
        #pragma unroll
        for (int j = 0; j < 8; ++j)
            v[j] = (n < MDIM) ? f2bf(Key[(size_t)(k0 + j) * MDIM + n]) : (short)0;
        *(short8*)(Keyfrag + (size_t)i * 8) = v;
    }
}

// k1: one wave per TWO b's. A-frags = raw fe (bf16) gathered per-lane into
// registers for both b's (16 b128 in flight per Kt step); uid_n folded into
// B (Key'); 1/||fe|| + mask applied to MFMA output rows. No block barriers.
__global__ __launch_bounds__(64)
void k1_attkey(const int* __restrict__ input_u, const int* __restrict__ input_uf,
               const float* __restrict__ uidW, const short* __restrict__ Keyfrag,
               float* __restrict__ att_key, float* __restrict__ Ssum,
               int user_num, int B)
{
    __shared__ float uidn[2][EDIM];
    __shared__ float invL[2][64];
    const int l = threadIdx.x;
    const int b0 = blockIdx.x * 2;
    const bool has2 = (b0 + 1) < B;
    const int b1 = has2 ? b0 + 1 : b0;

    const int u0 = input_u[b0];
    const int u1 = input_u[b1];
    int ufv0 = (l < NFR) ? input_uf[(size_t)b0 * NFR + l] : user_num;
    int ufv1 = (l < NFR) ? input_uf[(size_t)b1 * NFR + l] : user_num;
    float x00 = uidW[(size_t)u0 * EDIM + l];
    float x01 = uidW[(size_t)u0 * EDIM + 64 + l];
    float x10 = uidW[(size_t)u1 * EDIM + l];
    float x11 = uidW[(size_t)u1 * EDIM + 64 + l];
    short8 kb[4];
    #pragma unroll
    for (int Kt = 0; Kt < 4; ++Kt)
        kb[Kt] = *(const short8*)(Keyfrag + (size_t)(Kt * 64 + l) * 8);

    // friend ids for my 4 A-frag rows per b (pad rows -> zero uidW row, harmless)
    int fid0[4], fid1[4];
    #pragma unroll
    for (int Mt = 0; Mt < 4; ++Mt) {
        fid0[Mt] = __shfl(ufv0, Mt * 16 + (l & 15), 64);
        fid1[Mt] = __shfl(ufv1, Mt * 16 + (l & 15), 64);
    }
    const int eo = (l >> 4) * 8;

    float s0 = waveReduceSum(x00 * x00 + x01 * x01);
    float s1 = waveReduceSum(x10 * x10 + x11 * x11);
    float ui0 = 1.0f / fmaxf(sqrtf(s0), 1e-12f);
    float ui1 = 1.0f / fmaxf(sqrtf(s1), 1e-12f);
    uidn[0][l] = x00 * ui0; uidn[0][64 + l] = x01 * ui0;
    uidn[1][l] = x10 * ui1; uidn[1][64 + l] = x11 * ui1;
    __builtin_amdgcn_wave_barrier();

    f32x4 acc0[4], acc1[4];
    #pragma unroll
    for (int Mt = 0; Mt < 4; ++Mt) {
        acc0[Mt] = (f32x4){0.f, 0.f, 0.f, 0.f};
        acc1[Mt] = (f32x4){0.f, 0.f, 0.f, 0.f};
    }
    float fss0[4] = {0.f, 0.f, 0.f, 0.f};
    float fss1[4] = {0.f, 0.f, 0.f, 0.f};

    #pragma unroll
    for (int Kt = 0; Kt < 4; ++Kt) {
        float4 ga0[4], gb0[4], ga1[4], gb1[4];
        #pragma unroll
        for (int Mt = 0; Mt < 4; ++Mt) {
            const float* fp0 = uidW + (size_t)fid0[Mt] * EDIM + Kt * 32 + eo;
            ga0[Mt] = *(const float4*)fp0;
            gb0[Mt] = *(const float4*)(fp0 + 4);
            const float* fp1 = uidW + (size_t)fid1[Mt] * EDIM + Kt * 32 + eo;
            ga1[Mt] = *(const float4*)fp1;
            gb1[Mt] = *(const float4*)(fp1 + 4);
        }
        short8 kbv = kb[Kt];
        float4 u00 = *(const float4*)&uidn[0][Kt * 32 + eo];
        float4 u01 = *(const float4*)&uidn[0][Kt * 32 + eo + 4];
        float4 u10 = *(const float4*)&uidn[1][Kt * 32 + eo];
        float4 u11 = *(const float4*)&uidn[1][Kt * 32 + eo + 4];
        float4 ka, kbq;
        ka.x = bf2f(kbv[0]); ka.y = bf2f(kbv[1]);
        ka.z = bf2f(kbv[2]); ka.w = bf2f(kbv[3]);
        kbq.x = bf2f(kbv[4]); kbq.y = bf2f(kbv[5]);
        kbq.z = bf2f(kbv[6]); kbq.w = bf2f(kbv[7]);
        float4 p0a, p0b, p1a, p1b;
        p0a.x = u00.x * ka.x;  p0a.y = u00.y * ka.y;
        p0a.z = u00.z * ka.z;  p0a.w = u00.w * ka.w;
        p0b.x = u01.x * kbq.x; p0b.y = u01.y * kbq.y;
        p0b.z = u01.z * kbq.z; p0b.w = u01.w * kbq.w;
        p1a.x = u10.x * ka.x;  p1a.y = u10.y * ka.y;
        p1a.z = u10.z * ka.z;  p1a.w = u10.w * ka.w;
        p1b.x = u11.x * kbq.x; p1b.y = u11.y * kbq.y;
        p1b.z = u11.z * kbq.z; p1b.w = u11.w * kbq.w;
        short8 kbp0 = pack8(p0a, p0b);
        short8 kbp1 = pack8(p1a, p1b);
        #pragma unroll
        for (int Mt = 0; Mt < 4; ++Mt) {
            fss0[Mt] += ga0[Mt].x*ga0[Mt].x + ga0[Mt].y*ga0[Mt].y
                      + ga0[Mt].z*ga0[Mt].z + ga0[Mt].w*ga0[Mt].w
                      + gb0[Mt].x*gb0[Mt].x + gb0[Mt].y*gb0[Mt].y
                      + gb0[Mt].z*gb0[Mt].z + gb0[Mt].w*gb0[Mt].w;
            short8 a0 = pack8(ga0[Mt], gb0[Mt]);
            acc0[Mt] = __builtin_amdgcn_mfma_f32_16x16x32_bf16(a0, kbp0, acc0[Mt], 0, 0, 0);
            fss1[Mt] += ga1[Mt].x*ga1[Mt].x + ga1[Mt].y*ga1[Mt].y
                      + ga1[Mt].z*ga1[Mt].z + ga1[Mt].w*ga1[Mt].w
                      + gb1[Mt].x*gb1[Mt].x + gb1[Mt].y*gb1[Mt].y
                      + gb1[Mt].z*gb1[Mt].z + gb1[Mt].w*gb1[Mt].w;
            short8 a1 = pack8(ga1[Mt], gb1[Mt]);
            acc1[Mt] = __builtin_amdgcn_mfma_f32_16x16x32_bf16(a1, kbp1, acc1[Mt], 0, 0, 0);
        }
    }

    // per-row 1/||fe|| with mask folded in
    #pragma unroll
    for (int Mt = 0; Mt < 4; ++Mt) {
        int f = Mt * 16 + (l & 15);
        float t0 = fss0[Mt];
        t0 += __shfl_xor(t0, 16, 64);
        t0 += __shfl_xor(t0, 32, 64);
        float fn0 = (f < NFR && fid0[Mt] != user_num) ? 1.f : 0.f;
        invL[0][f] = fn0 / fmaxf(sqrtf(t0), 1e-12f);
        float t1 = fss1[Mt];
        t1 += __shfl_xor(t1, 16, 64);
        t1 += __shfl_xor(t1, 32, 64);
        float fn1 = (f < NFR && fid1[Mt] != user_num) ? 1.f : 0.f;
        invL[1][f] = fn1 / fmaxf(sqrtf(t1), 1e-12f);
    }
    __builtin_amdgcn_wave_barrier();

    const int m = l & 15;
    if (m < MDIM) {
        float* Ss0 = Ssum + (size_t)(b0 & (NSLICE - 1)) * NCOL;
        float* Ss1 = Ssum + (size_t)(b1 & (NSLICE - 1)) * NCOL;
        #pragma unroll
        for (int Mt = 0; Mt < 4; ++Mt) {
            const int fbase = Mt * 16 + (l >> 4) * 4;
            #pragma unroll
            for (int r = 0; r < 4; ++r) {
                int f = fbase + r;
                if (f < NFR) {
                    float v0 = acc0[Mt][r] * invL[0][f];
                    att_key[((size_t)b0 * NFR + f) * MDIM + m] = v0;
                    atomicAdd(&Ss0[f * MDIM + m], __expf(v0));
                    if (has2) {
                        float v1 = acc1[Mt][r] * invL[1][f];
                        att_key[((size_t)b1 * NFR + f) * MDIM + m] = v1;
                        atomicAdd(&Ss1[f * MDIM + m], __expf(v1));
                    }
                }
            }
        }
    }
}

// k2b: merge NSLICE partials per column -> inv denominator
__global__ __launch_bounds__(256)
void k2b_merge(const float* __restrict__ Ssum, float* __restrict__ ise)
{
    int col = blockIdx.x * 256 + threadIdx.x;
    if (col >= NCOL) return;
    float S = 0.f;
    #pragma unroll
    for (int s = 0; s < NSLICE; ++s) S += Ssum[s * NCOL + col];
    ise[col] = 1.0f / S;
}

// k3: wave-per-b, barrier-free. Phase 1 now issues ALL 32 row-gathers up front
// (two 16-load register batches) so HBM/L3 latency overlaps the full m-fold.
__global__ __launch_bounds__(256, 2)
void k3_final(const int* __restrict__ input_u, const int* __restrict__ input_i,
              const int* __restrict__ input_uf, const float* __restrict__ uidW,
              const float* __restrict__ iidW, const float* __restrict__ i_bias,
              const float* __restrict__ Mem, const short* __restrict__ WAfrag,
              const float* __restrict__ BA, const float* __restrict__ U_omega,
              const float* __restrict__ att_key, const float* __restrict__ ise,
              float* __restrict__ out, int user_num, int B)
{
    __shared__ short f2F4[4][64 * EDIM];   // 64 KB
    __shared__ float amL4[4][NCOL];        // 6.25 KB
    __shared__ float jxL4[4][64];          // 1 KB
    const int w = threadIdx.x >> 6, l = threadIdx.x & 63;
    const int b = blockIdx.x * 4 + w;
    if (b >= B) return;
    short* f2F = f2F4[w];
    float* amL = amL4[w];
    float* jxL = jxL4[w];

    const int u = input_u[b];
    const int ii = input_i[b];
    const float ib = i_bias[ii];
    int ufv = (l < NFR) ? input_uf[(size_t)b * NFR + l] : user_num;

    const int kg = l & 15, fl = l >> 4;
    const int e0 = kg * 8;

    // am = fn * exp(att_key) * ise  (max-free)
    #pragma unroll
    for (int c = 0; c < 7; ++c) {
        int i = l + 64 * c;
        if (i < NCOL) {
            float ak = att_key[(size_t)b * NCOL + i];
            int fid = __shfl(ufv, i >> 3, 64);
            amL[i] = (fid != user_num) ? __expf(ak) * ise[i] : 0.f;
        }
    }

    float4 mA[MDIM], mB[MDIM];            // Mem slice for this lane's e-octet
    #pragma unroll
    for (int m = 0; m < MDIM; ++m) {
        mA[m] = *(const float4*)&Mem[m * EDIM + e0];
        mB[m] = *(const float4*)&Mem[m * EDIM + e0 + 4];
    }
    __builtin_amdgcn_wave_barrier();

    // phase 1: prefetch all 32 gathers (rows f = (k>>2)*16 + (k&3)*4 + fl)
    int fidv[16];
    #pragma unroll
    for (int k = 0; k < 16; ++k) {
        int f = (k >> 2) * 16 + (k & 3) * 4 + fl;
        fidv[k] = __shfl(ufv, f, 64);
    }
    float4 g0a[8], g1a[8];
    #pragma unroll
    for (int k = 0; k < 8; ++k) {
        int f = (k >> 2) * 16 + (k & 3) * 4 + fl;
        if (f < NFR) {
            const float* fp = uidW + (size_t)fidv[k] * EDIM + e0;
            g0a[k] = *(const float4*)fp;
            g1a[k] = *(const float4*)(fp + 4);
        }
    }
    float4 g0b[8], g1b[8];
    #pragma unroll
    for (int k = 0; k < 8; ++k) {
        int f = ((k >> 2) + 2) * 16 + (k & 3) * 4 + fl;
        if (f < NFR) {
            const float* fp = uidW + (size_t)fidv[8 + k] * EDIM + e0;
            g0b[k] = *(const float4*)fp;
            g1b[k] = *(const float4*)(fp + 4);
        }
    }

    auto comp = [&](int f, float4 g0, float4 g1) {
        short8 outv = {0, 0, 0, 0, 0, 0, 0, 0};
        if (f < NFR) {
            float4 am0 = *(const float4*)&amL[f * 8];
            float4 am1 = *(const float4*)&amL[f * 8 + 4];
            float4 fa = {0.f, 0.f, 0.f, 0.f}, fb = {0.f, 0.f, 0.f, 0.f};
            #pragma unroll
            for (int m = 0; m < 4; ++m) {
                float c0 = (&am0.x)[m], c1 = (&am1.x)[m];
                fa.x += c0 * mA[m].x + c1 * mA[m + 4].x;
                fa.y += c0 * mA[m].y + c1 * mA[m + 4].y;
                fa.z += c0 * mA[m].z + c1 * mA[m + 4].z;
                fa.w += c0 * mA[m].w + c1 * mA[m + 4].w;
                fb.x += c0 * mB[m].x + c1 * mB[m + 4].x;
                fb.y += c0 * mB[m].y + c1 * mB[m + 4].y;
                fb.z += c0 * mB[m].z + c1 * mB[m + 4].z;
                fb.w += c0 * mB[m].w + c1 * mB[m + 4].w;
            }
            // masked friends: am==0 -> fa=fb=0 -> f2=0 (matches reference)
            float4 pA, pB;
            pA.x = fa.x * g0.x; pA.y = fa.y * g0.y;
            pA.z = fa.z * g0.z; pA.w = fa.w * g0.w;
            pB.x = fb.x * g1.x; pB.y = fb.y * g1.y;
            pB.z = fb.z * g1.z; pB.w = fb.w * g1.w;
            outv = pack8(pA, pB);
        }
        *(short8*)&f2F[fragOff(f, e0)] = outv;
    };
    #pragma unroll
    for (int k = 0; k < 8; ++k)
        comp((k >> 2) * 16 + (k & 3) * 4 + fl, g0a[k], g1a[k]);
    #pragma unroll
    for (int k = 0; k < 8; ++k)
        comp(((k >> 2) + 2) * 16 + (k & 3) * 4 + fl, g0b[k], g1b[k]);
    __builtin_amdgcn_wave_barrier();

    // phase 2: h = f2(64x128) x WA(128x64), 64 MFMAs per wave
    const int sl = slotR(l);
    f32x4 acc[4][4];
    #pragma unroll
    for (int Mt = 0; Mt < 4; ++Mt)
        #pragma unroll
        for (int Nt = 0; Nt < 4; ++Nt) acc[Mt][Nt] = (f32x4){0.f, 0.f, 0.f, 0.f};
    #pragma unroll
    for (int Kt = 0; Kt < 4; ++Kt) {
        short8 a[4];
        #pragma unroll
        for (int Mt = 0; Mt < 4; ++Mt)
            a[Mt] = *(const short8*)&f2F[(((Mt << 2) | Kt) * 64 + sl) * 8];
        #pragma unroll
        for (int Nt = 0; Nt < 4; ++Nt) {
            short8 bf = *(const short8*)(WAfrag + (size_t)(((Nt << 2) | Kt) * 64 + l) * 8);
            #pragma unroll
            for (int Mt = 0; Mt < 4; ++Mt)
                acc[Mt][Nt] = __builtin_amdgcn_mfma_f32_16x16x32_bf16(a[Mt], bf, acc[Mt][Nt], 0, 0, 0);
        }
    }

    // phase 3: fold relu(h+BA)*U_omega over all 64 cols -> per-friend p
    float ba4[4], uo4[4];
    #pragma unroll
    for (int Nt = 0; Nt < 4; ++Nt) {
        ba4[Nt] = BA[Nt * 16 + kg];
        uo4[Nt] = U_omega[Nt * 16 + kg];
    }
    float v[16];
    #pragma unroll
    for (int Mt = 0; Mt < 4; ++Mt)
        #pragma unroll
        for (int r = 0; r < 4; ++r) {
            float sv = 0.f;
            #pragma unroll
            for (int Nt = 0; Nt < 4; ++Nt)
                sv += fmaxf(acc[Mt][Nt][r] + ba4[Nt], 0.f) * uo4[Nt];
            v[Mt * 4 + r] = sv;
        }

    const bool c0 = l & 1, c1 = l & 2, c2 = l & 4, c3 = l & 8;
    #pragma unroll
    for (int k = 0; k < 8; ++k) {
        float lo = v[k], hi = v[k + 8];
        float send = c0 ? lo : hi;
        float recv = __shfl_xor(send, 1, 64);
        v[k] = c0 ? (hi + recv) : (lo + recv);
    }
    #pragma unroll
    for (int k = 0; k < 4; ++k) {
        float lo = v[k], hi = v[k + 4];
        float send = c1 ? lo : hi;
        float recv = __shfl_xor(send, 2, 64);
        v[k] = c1 ? (hi + recv) : (lo + recv);
    }
    #pragma unroll
    for (int k = 0; k < 2; ++k) {
        float lo = v[k], hi = v[k + 2];
        float send = c2 ? lo : hi;
        float recv = __shfl_xor(send, 4, 64);
        v[k] = c2 ? (hi + recv) : (lo + recv);
    }
    {
        float lo = v[0], hi = v[1];
        float send = c3 ? lo : hi;
        float recv = __shfl_xor(send, 8, 64);
        v[0] = c3 ? (hi + recv) : (lo + recv);
    }
    const int vIdx = ((l & 1) << 3) | ((l & 2) << 1) | ((l & 4) >> 1) | ((l & 8) >> 3);
    const int fLane = (vIdx >> 2) * 16 + (l >> 4) * 4 + (vIdx & 3);

    int ufF = __shfl(ufv, fLane, 64);
    float jv = 0.f;
    if (fLane < NFR && ufF != user_num) jv = __expf(v[0]);
    jxL[fLane] = jv;
    float winv = 1.0f / (waveReduceSum(jv) + 1e-8f);
    __builtin_amdgcn_wave_barrier();

    // phase 4: friend-weighted sum of f2 (pad rows are zero, jx pad = 0)
    float pa[8] = {0.f, 0.f, 0.f, 0.f, 0.f, 0.f, 0.f, 0.f};
    #pragma unroll
    for (int hi = 0; hi < 4; ++hi) {
        #pragma unroll
        for (int lo = 0; lo < 4; ++lo) {
            int f = hi * 16 + lo * 4 + fl;
            float jf = jxL[f];
            short8 vv = *(const short8*)&f2F[fragOff(f, e0)];
            #pragma unroll
            for (int j = 0; j < 8; ++j) pa[j] += jf * bf2f(vv[j]);
        }
    }
    #pragma unroll
    for (int j = 0; j < 8; ++j) {
        pa[j] += __shfl_xor(pa[j], 16, 64);
        pa[j] += __shfl_xor(pa[j], 32, 64);
    }

    // epilogue: score = sum_e (uid+friend)*iid + i_bias (4x duplicated -> *0.25)
    const float* up = uidW + (size_t)u * EDIM + e0;
    const float* ip = iidW + (size_t)ii * EDIM + e0;
    float4 u0 = *(const float4*)up;
    float4 u1 = *(const float4*)(up + 4);
    float4 i0 = *(const float4*)ip;
    float4 i1 = *(const float4*)(ip + 4);
    float sc = 0.f;
    #pragma unroll
    for (int j = 0; j < 4; ++j) {
        sc += ((&u0.x)[j] + pa[j] * winv) * (&i0.x)[j];
        sc += ((&u1.x)[j] + pa[j + 4] * winv) * (&i1.x)[j];
    }
    float red = waveReduceSum(sc);
    if (l == 0) out[b] = red * 0.25f + ib;
}

extern "C" void kernel_launch(void* const* d_in, const int* in_sizes, int n_in,
                              void* d_out, int out_size, void* d_ws, size_t ws_size,
                              hipStream_t stream)
{
    const int*   input_u  = (const int*)d_in[0];
    const int*   input_i  = (const int*)d_in[1];
    const int*   input_uf = (const int*)d_in[2];
    const float* uidW     = (const float*)d_in[3];
    const float* iidW     = (const float*)d_in[4];
    const float* i_bias   = (const float*)d_in[5];
    const float* Key      = (const float*)d_in[6];
    const float* Mem      = (const float*)d_in[7];
    const float* WA       = (const float*)d_in[8];
    const float* BA       = (const float*)d_in[9];
    const float* U_om     = (const float*)d_in[10];

    const int B = in_sizes[0];
    const int user_num = in_sizes[3] / EDIM - 1;

    float* att  = (float*)d_ws;                                  // B*400
    float* Ssum = att + (size_t)B * NCOL;                        // 64*400
    float* ise  = Ssum + NSLICE * NCOL;                          // 400
    short* WAfrag  = (short*)(ise + NCOL);                       // 8192
    short* Keyfrag = WAfrag + 4 * 4 * 64 * 8;                    // 2048

    const int nb1 = (B + 1) / 2;
    const int nb3 = (B + 3) / 4;
    k0_prep<<<5, 256, 0, stream>>>(WA, Key, WAfrag, Keyfrag, Ssum);
    k1_attkey<<<nb1, 64, 0, stream>>>(input_u, input_uf, uidW, Keyfrag, att,
                                      Ssum, user_num, B);
    k2b_merge<<<2, 256, 0, stream>>>(Ssum, ise);
    k3_final<<<nb3, 256, 0, stream>>>(input_u, input_i, input_uf, uidW, iidW, i_bias,
                                      Mem, WAfrag, BA, U_om, att, ise,
                                      (float*)d_out, user_num, B);
}